// Round 1
// baseline (22.007 us; speedup 1.0000x reference)
//
#include <hip/hip_runtime.h>

#define VOC 64

// Kernel 1: build the 64-entry lookup table.
// lut[v] = (c0*v + a0) % 64 where a0 = argmax(W[v,0:64]+b[0:64]),
//          c0 = argmax(W[v,64:128]+b[64:128]); lut[v] = -1 if c0 == 0
//          (edward2 zeroes the c==0 row of one_hot_multiply -> zero output).
__global__ void build_lut_kernel(const float* __restrict__ W,
                                 const float* __restrict__ b,
                                 int* __restrict__ lut) {
    int v = threadIdx.x;
    if (v >= VOC) return;
    const float* row = W + v * (2 * VOC);

    // argmax of loc logits (first occurrence on ties, matching jnp.argmax)
    float bestL = row[0] + b[0];
    int aL = 0;
    for (int j = 1; j < VOC; ++j) {
        float x = row[j] + b[j];
        if (x > bestL) { bestL = x; aL = j; }
    }
    // argmax of scale logits
    float bestS = row[VOC] + b[VOC];
    int aS = 0;
    for (int j = 1; j < VOC; ++j) {
        float x = row[VOC + j] + b[VOC + j];
        if (x > bestS) { bestS = x; aS = j; }
    }
    lut[v] = (aS == 0) ? -1 : (aS * v + aL) % VOC;
}

// Kernel 2: per row (B*L rows of 64 floats): argmax -> lut -> one-hot write.
// 16 lanes per row, float4 per lane (fully coalesced 16B/lane).
__global__ void flow_fwd_kernel(const float* __restrict__ in,
                                float* __restrict__ out,
                                const int* __restrict__ lut,
                                int n_rows) {
    __shared__ int s_lut[VOC];
    if (threadIdx.x < VOC) s_lut[threadIdx.x] = lut[threadIdx.x];
    __syncthreads();

    int t = blockIdx.x * blockDim.x + threadIdx.x;
    int row = t >> 4;   // 16 lanes per row
    int sub = t & 15;
    if (row >= n_rows) return;

    const float4 vin =
        *reinterpret_cast<const float4*>(in + (size_t)row * VOC + sub * 4);

    // local argmax over 4 elements (ascending order + strict > keeps first max)
    float bv = vin.x;
    int bi = sub * 4;
    if (vin.y > bv) { bv = vin.y; bi = sub * 4 + 1; }
    if (vin.z > bv) { bv = vin.z; bi = sub * 4 + 2; }
    if (vin.w > bv) { bv = vin.w; bi = sub * 4 + 3; }

    // butterfly argmax across the 16 lanes of this row
    // lexicographic max on (value, -index) is associative+commutative
    #pragma unroll
    for (int off = 1; off < 16; off <<= 1) {
        float ov = __shfl_xor(bv, off, 16);
        int   oi = __shfl_xor(bi, off, 16);
        if (ov > bv || (ov == bv && oi < bi)) { bv = ov; bi = oi; }
    }

    int oidx = s_lut[bi];   // -1 => zero row

    float4 vout;
    vout.x = (oidx == sub * 4)     ? 1.0f : 0.0f;
    vout.y = (oidx == sub * 4 + 1) ? 1.0f : 0.0f;
    vout.z = (oidx == sub * 4 + 2) ? 1.0f : 0.0f;
    vout.w = (oidx == sub * 4 + 3) ? 1.0f : 0.0f;
    *reinterpret_cast<float4*>(out + (size_t)row * VOC + sub * 4) = vout;
}

extern "C" void kernel_launch(void* const* d_in, const int* in_sizes, int n_in,
                              void* d_out, int out_size, void* d_ws, size_t ws_size,
                              hipStream_t stream) {
    const float* inputs = (const float*)d_in[0];  // (B, L, 64) f32 one-hot
    const float* W      = (const float*)d_in[1];  // (64, 128) f32
    const float* b      = (const float*)d_in[2];  // (128,) f32

    float* out = (float*)d_out;
    int*   lut = (int*)d_ws;                      // 64 ints of scratch

    int n_rows = in_sizes[0] / VOC;               // B*L = 131072

    build_lut_kernel<<<1, VOC, 0, stream>>>(W, b, lut);

    int threads = 256;
    int total   = n_rows * 16;                    // 16 lanes per row
    int blocks  = (total + threads - 1) / threads;
    flow_fwd_kernel<<<blocks, threads, 0, stream>>>(inputs, out, lut, n_rows);
}

// Round 2
// 20.875 us; speedup vs baseline: 1.0542x; 1.0542x over previous
//
#include <hip/hip_runtime.h>

#define VOC 64

// Fused kernel:
//  prologue (per block, one-time): build the 64-entry LUT
//    lut[v] = (c0*v + a0) % 64, a0 = argmax(W[v,0:64]+b[0:64]),
//             c0 = argmax(W[v,64:128]+b[64:128]); -1 if c0==0 (zero row).
//    4 threads per v: float4 loads + width-4 shuffle argmax combine.
//  main loop (grid-stride): per 64-float row, argmax via 16-lane butterfly,
//    LUT gather, one-hot float4 write. Pure streaming, memory-bound.
__global__ __launch_bounds__(256) void flow_fused_kernel(
    const float* __restrict__ in,
    const float* __restrict__ W,
    const float* __restrict__ b,
    float* __restrict__ out,
    int n_chunks)            // n_rows * 16 float4-chunks
{
    __shared__ float s_b[2 * VOC];
    __shared__ int   s_lut[VOC];

    if (threadIdx.x < 2 * VOC) s_b[threadIdx.x] = b[threadIdx.x];
    __syncthreads();

    // ---- LUT build: thread (v,q), v = tid>>2, q = tid&3 ----
    {
        int v = threadIdx.x >> 2;
        int q = threadIdx.x & 3;
        const float4* rowL = reinterpret_cast<const float4*>(W + v * 2 * VOC) + q * 4;
        const float4* rowS = rowL + (VOC / 4);               // +64 floats
        const float4* b4   = reinterpret_cast<const float4*>(s_b);

        float bvL = -3.402823466e+38f; int biL = 0;
        float bvS = -3.402823466e+38f; int biS = 0;
        #pragma unroll
        for (int k = 0; k < 4; ++k) {
            float4 wl = rowL[k];
            float4 ws = rowS[k];
            float4 bl = b4[q * 4 + k];
            float4 bs = b4[(VOC / 4) + q * 4 + k];
            float xs0 = wl.x + bl.x, xs1 = wl.y + bl.y, xs2 = wl.z + bl.z, xs3 = wl.w + bl.w;
            float ys0 = ws.x + bs.x, ys1 = ws.y + bs.y, ys2 = ws.z + bs.z, ys3 = ws.w + bs.w;
            int base = q * 16 + k * 4;
            // ascending index + strict > keeps first occurrence (jnp.argmax)
            if (xs0 > bvL) { bvL = xs0; biL = base;     }
            if (xs1 > bvL) { bvL = xs1; biL = base + 1; }
            if (xs2 > bvL) { bvL = xs2; biL = base + 2; }
            if (xs3 > bvL) { bvL = xs3; biL = base + 3; }
            if (ys0 > bvS) { bvS = ys0; biS = base;     }
            if (ys1 > bvS) { bvS = ys1; biS = base + 1; }
            if (ys2 > bvS) { bvS = ys2; biS = base + 2; }
            if (ys3 > bvS) { bvS = ys3; biS = base + 3; }
        }
        // combine the 4 partials (lanes v*4+q are adjacent): lexicographic max
        #pragma unroll
        for (int off = 1; off < 4; off <<= 1) {
            float ov = __shfl_xor(bvL, off, 4);
            int   oi = __shfl_xor(biL, off, 4);
            if (ov > bvL || (ov == bvL && oi < biL)) { bvL = ov; biL = oi; }
            ov = __shfl_xor(bvS, off, 4);
            oi = __shfl_xor(biS, off, 4);
            if (ov > bvS || (ov == bvS && oi < biS)) { bvS = ov; biS = oi; }
        }
        if (q == 0) s_lut[v] = (biS == 0) ? -1 : (biS * v + biL) % VOC;
    }
    __syncthreads();

    // ---- main grid-stride loop: 16 lanes per row, float4 per lane ----
    int stride = gridDim.x * blockDim.x;
    for (int t = blockIdx.x * blockDim.x + threadIdx.x; t < n_chunks; t += stride) {
        int sub = t & 15;
        const float4 vin = *reinterpret_cast<const float4*>(in + (size_t)t * 4);

        float bv = vin.x;
        int   bi = sub * 4;
        if (vin.y > bv) { bv = vin.y; bi = sub * 4 + 1; }
        if (vin.z > bv) { bv = vin.z; bi = sub * 4 + 2; }
        if (vin.w > bv) { bv = vin.w; bi = sub * 4 + 3; }

        #pragma unroll
        for (int off = 1; off < 16; off <<= 1) {
            float ov = __shfl_xor(bv, off, 16);
            int   oi = __shfl_xor(bi, off, 16);
            if (ov > bv || (ov == bv && oi < bi)) { bv = ov; bi = oi; }
        }

        int oidx = s_lut[bi];        // -1 => zero row
        int base = sub * 4;
        float4 vo;
        vo.x = (oidx == base)     ? 1.0f : 0.0f;
        vo.y = (oidx == base + 1) ? 1.0f : 0.0f;
        vo.z = (oidx == base + 2) ? 1.0f : 0.0f;
        vo.w = (oidx == base + 3) ? 1.0f : 0.0f;
        *reinterpret_cast<float4*>(out + (size_t)t * 4) = vo;
    }
}

extern "C" void kernel_launch(void* const* d_in, const int* in_sizes, int n_in,
                              void* d_out, int out_size, void* d_ws, size_t ws_size,
                              hipStream_t stream) {
    const float* inputs = (const float*)d_in[0];  // (B, L, 64) f32 one-hot
    const float* W      = (const float*)d_in[1];  // (64, 128) f32
    const float* b      = (const float*)d_in[2];  // (128,) f32
    float* out = (float*)d_out;

    int n_rows   = in_sizes[0] / VOC;             // B*L = 131072
    int n_chunks = n_rows * 16;                   // float4 chunks

    int threads = 256;
    int blocks  = (n_chunks + threads - 1) / threads;
    if (blocks > 2048) blocks = 2048;             // 8 blocks/CU, grid-stride rest

    flow_fused_kernel<<<blocks, threads, 0, stream>>>(inputs, W, b, out, n_chunks);
}

// Round 3
// 18.459 us; speedup vs baseline: 1.1922x; 1.1309x over previous
//
#include <hip/hip_runtime.h>

#define VOC 64
#define CHUNKS 8            // float4 chunks per thread (128 B in, 128 B out)
#define TPB 256

// Fully fused, single dispatch.
//  - LUT: lut[v] = (c0*v + a0) % 64 with a0 = argmax(W[v,0:64]+b[0:64]),
//         c0 = argmax(W[v,64:128]+b[64:128]); -1 when c0 == 0 (zero row).
//  - Load order: W/b first, then all 8 input float4 loads. The LUT compute's
//    waitcnt drains only the (first-issued) W/b loads, so the 128 B/thread
//    of streaming input stays in flight under the prologue.
//  - Input is an exact one-hot (0.0 / 1.0), so "argmax" = locate the 1.0:
//    one __ballot + one __shfl per 16-lane row group.
__global__ __launch_bounds__(TPB) void flow_fused_kernel(
    const float* __restrict__ in,
    const float* __restrict__ W,
    const float* __restrict__ b,
    float* __restrict__ out,
    int n_chunks)
{
    __shared__ int s_lut[VOC];

    const int tid = threadIdx.x;
    const size_t base = (size_t)blockIdx.x * (TPB * CHUNKS) + tid;
    const float4* in4  = reinterpret_cast<const float4*>(in);
    float4*       out4 = reinterpret_cast<float4*>(out);

    // ---- 1. issue LUT loads (W slices + b slices) FIRST ----
    const int v = tid >> 2;          // vocab row this thread helps argmax
    const int q = tid & 3;           // quarter of the row
    const float4* rowL = reinterpret_cast<const float4*>(W + v * 2 * VOC) + q * 4;
    const float4* rowS = rowL + (VOC / 4);   // +64 floats
    const float4* b4   = reinterpret_cast<const float4*>(b);

    float4 wL[4], wS[4], bL[4], bS[4];
    #pragma unroll
    for (int k = 0; k < 4; ++k) {
        wL[k] = rowL[k];
        wS[k] = rowS[k];
        bL[k] = b4[q * 4 + k];
        bS[k] = b4[16 + q * 4 + k];
    }

    // ---- 2. issue ALL streaming input loads (stay in flight) ----
    float4 vin[CHUNKS];
    #pragma unroll
    for (int i = 0; i < CHUNKS; ++i) {
        size_t c = base + (size_t)i * TPB;
        if (c < (size_t)n_chunks) vin[i] = in4[c];
        else                      vin[i] = make_float4(0.f, 0.f, 0.f, 0.f);
    }

    // ---- 3. LUT build (waits only on W/b; inputs still airborne) ----
    {
        float bvL = -3.402823466e+38f; int biL = 0;
        float bvS = -3.402823466e+38f; int biS = 0;
        #pragma unroll
        for (int k = 0; k < 4; ++k) {
            float x0 = wL[k].x + bL[k].x, x1 = wL[k].y + bL[k].y;
            float x2 = wL[k].z + bL[k].z, x3 = wL[k].w + bL[k].w;
            float y0 = wS[k].x + bS[k].x, y1 = wS[k].y + bS[k].y;
            float y2 = wS[k].z + bS[k].z, y3 = wS[k].w + bS[k].w;
            int ib = q * 16 + k * 4;
            // ascending index + strict > keeps first occurrence (jnp.argmax)
            if (x0 > bvL) { bvL = x0; biL = ib;     }
            if (x1 > bvL) { bvL = x1; biL = ib + 1; }
            if (x2 > bvL) { bvL = x2; biL = ib + 2; }
            if (x3 > bvL) { bvL = x3; biL = ib + 3; }
            if (y0 > bvS) { bvS = y0; biS = ib;     }
            if (y1 > bvS) { bvS = y1; biS = ib + 1; }
            if (y2 > bvS) { bvS = y2; biS = ib + 2; }
            if (y3 > bvS) { bvS = y3; biS = ib + 3; }
        }
        // combine the 4 partials (adjacent lanes): lexicographic max
        #pragma unroll
        for (int off = 1; off < 4; off <<= 1) {
            float ov = __shfl_xor(bvL, off, 4);
            int   oi = __shfl_xor(biL, off, 4);
            if (ov > bvL || (ov == bvL && oi < biL)) { bvL = ov; biL = oi; }
            ov = __shfl_xor(bvS, off, 4);
            oi = __shfl_xor(biS, off, 4);
            if (ov > bvS || (ov == bvS && oi < biS)) { bvS = ov; biS = oi; }
        }
        if (q == 0) s_lut[v] = (biS == 0) ? -1 : (biS * v + biL) % VOC;
    }
    __syncthreads();

    // ---- 4. stream: locate the 1.0, LUT, one-hot write ----
    const int lane = tid & 63;
    const int grp  = lane >> 4;          // 16-lane row group within wave
    const int gb   = lane & ~15;         // group base lane
    const int sub  = tid & 15;           // this lane's quarter of the row
    const int b4i  = sub << 2;

    #pragma unroll
    for (int i = 0; i < CHUNKS; ++i) {
        size_t c = base + (size_t)i * TPB;
        float4 x = vin[i];
        int li = -1;                      // local index of the 1.0 (0..3)
        if (x.x > 0.5f) li = 0;
        if (x.y > 0.5f) li = 1;
        if (x.z > 0.5f) li = 2;
        if (x.w > 0.5f) li = 3;
        unsigned long long m = __ballot(li >= 0);
        unsigned gm = (unsigned)((m >> (grp * 16)) & 0xFFFFull);
        if (gm == 0) continue;            // fully-inactive tail group
        int wlane = __builtin_ctz(gm);    // winning sub-lane (0..15)
        int lw    = __shfl(li, gb + wlane, 64);
        int bi    = (wlane << 2) + lw;    // vocab index of the input 1.0

        int oidx = s_lut[bi];             // -1 => zero row

        float4 vo;
        vo.x = (oidx == b4i)     ? 1.0f : 0.0f;
        vo.y = (oidx == b4i + 1) ? 1.0f : 0.0f;
        vo.z = (oidx == b4i + 2) ? 1.0f : 0.0f;
        vo.w = (oidx == b4i + 3) ? 1.0f : 0.0f;
        if (c < (size_t)n_chunks)
            out4[c] = vo;
    }
}

extern "C" void kernel_launch(void* const* d_in, const int* in_sizes, int n_in,
                              void* d_out, int out_size, void* d_ws, size_t ws_size,
                              hipStream_t stream) {
    const float* inputs = (const float*)d_in[0];  // (B, L, 64) f32 one-hot
    const float* W      = (const float*)d_in[1];  // (64, 128) f32
    const float* b      = (const float*)d_in[2];  // (128,) f32
    float* out = (float*)d_out;

    int n_rows   = in_sizes[0] / VOC;             // B*L = 131072
    int n_chunks = n_rows * 16;                   // float4 chunks (mult of 16)

    int per_block = TPB * CHUNKS;
    int blocks = (n_chunks + per_block - 1) / per_block;  // 1024 for B=16,L=8192

    flow_fused_kernel<<<blocks, TPB, 0, stream>>>(inputs, W, b, out, n_chunks);
}

// Round 5
// 17.107 us; speedup vs baseline: 1.2865x; 1.0790x over previous
//
#include <hip/hip_runtime.h>

#define VOC 64
#define CHUNKS 8            // float4 chunks per thread (128 B in, 128 B out)
#define TPB 512

typedef float f32x4 __attribute__((ext_vector_type(4)));

// Single fused dispatch.
//  LUT: lut[v] = (c0*v + a0) % 64, a0 = argmax(W[v,0:64]+b[0:64]),
//       c0 = argmax(W[v,64:128]+b[64:128]); -1 when c0 == 0 (zero row,
//       because edward2 masks the c==0 slice of one_hot_multiply).
//  Load order: W/b (threads 0..255) first, then all 8 streaming input
//  loads -> the LUT compute's waitcnt drains only W/b; input stays in
//  flight under the prologue.
//  Input rows are exact one-hots (0.0/1.0): locate the 1.0 with three
//  ballots (presence + 2 bits of sub-index) -- no shuffle in the chain.
__global__ __launch_bounds__(TPB) void flow_fused_kernel(
    const float* __restrict__ in,
    const float* __restrict__ W,
    const float* __restrict__ b,
    float* __restrict__ out,
    int n_chunks)
{
    __shared__ int s_lut[VOC];

    const int tid = threadIdx.x;
    const size_t base = (size_t)blockIdx.x * (TPB * CHUNKS) + tid;
    const f32x4* in4  = reinterpret_cast<const f32x4*>(in);
    f32x4*       out4 = reinterpret_cast<f32x4*>(out);

    // ---- 1. issue LUT source loads FIRST (threads 0..255) ----
    f32x4 wL[4], wS[4], bL[4], bS[4];
    const int v = tid >> 2;          // vocab row (for tid < 256)
    const int q = tid & 3;           // quarter of the row
    if (tid < 256) {
        const f32x4* rowL = reinterpret_cast<const f32x4*>(W + v * 2 * VOC) + q * 4;
        const f32x4* rowS = rowL + (VOC / 4);   // +64 floats
        const f32x4* b4   = reinterpret_cast<const f32x4*>(b);
        #pragma unroll
        for (int k = 0; k < 4; ++k) {
            wL[k] = rowL[k];
            wS[k] = rowS[k];
            bL[k] = b4[q * 4 + k];
            bS[k] = b4[16 + q * 4 + k];
        }
    }

    // ---- 2. issue ALL streaming input loads (nontemporal, stay in flight) ----
    f32x4 vin[CHUNKS];
    #pragma unroll
    for (int i = 0; i < CHUNKS; ++i) {
        size_t c = base + (size_t)i * TPB;
        if (c < (size_t)n_chunks) vin[i] = __builtin_nontemporal_load(&in4[c]);
        else                      vin[i] = (f32x4){0.f, 0.f, 0.f, 0.f};
    }

    // ---- 3. LUT build (waits only on W/b; inputs still airborne) ----
    if (tid < 256) {
        float bvL = -3.402823466e+38f; int biL = 0;
        float bvS = -3.402823466e+38f; int biS = 0;
        #pragma unroll
        for (int k = 0; k < 4; ++k) {
            float x0 = wL[k].x + bL[k].x, x1 = wL[k].y + bL[k].y;
            float x2 = wL[k].z + bL[k].z, x3 = wL[k].w + bL[k].w;
            float y0 = wS[k].x + bS[k].x, y1 = wS[k].y + bS[k].y;
            float y2 = wS[k].z + bS[k].z, y3 = wS[k].w + bS[k].w;
            int ib = q * 16 + k * 4;
            // ascending index + strict > keeps first occurrence (jnp.argmax)
            if (x0 > bvL) { bvL = x0; biL = ib;     }
            if (x1 > bvL) { bvL = x1; biL = ib + 1; }
            if (x2 > bvL) { bvL = x2; biL = ib + 2; }
            if (x3 > bvL) { bvL = x3; biL = ib + 3; }
            if (y0 > bvS) { bvS = y0; biS = ib;     }
            if (y1 > bvS) { bvS = y1; biS = ib + 1; }
            if (y2 > bvS) { bvS = y2; biS = ib + 2; }
            if (y3 > bvS) { bvS = y3; biS = ib + 3; }
        }
        // combine the 4 partials (adjacent lanes): lexicographic max
        #pragma unroll
        for (int off = 1; off < 4; off <<= 1) {
            float ov = __shfl_xor(bvL, off, 4);
            int   oi = __shfl_xor(biL, off, 4);
            if (ov > bvL || (ov == bvL && oi < biL)) { bvL = ov; biL = oi; }
            ov = __shfl_xor(bvS, off, 4);
            oi = __shfl_xor(biS, off, 4);
            if (ov > bvS || (ov == bvS && oi < biS)) { bvS = ov; biS = oi; }
        }
        if (q == 0) s_lut[v] = (biS == 0) ? -1 : (biS * v + biL) % VOC;
    }
    __syncthreads();

    // ---- 4. stream: locate the 1.0 via 3 ballots, LUT, one-hot write ----
    const int lane = tid & 63;
    const int grp  = lane >> 4;          // 16-lane row group within wave
    const int sub  = tid & 15;           // this lane's quarter of the row
    const int b4i  = sub << 2;

    #pragma unroll
    for (int i = 0; i < CHUNKS; ++i) {
        size_t c = base + (size_t)i * TPB;
        f32x4 x = vin[i];
        int li = -1;                      // local index of the 1.0 (0..3)
        if (x.x > 0.5f) li = 0;
        if (x.y > 0.5f) li = 1;
        if (x.z > 0.5f) li = 2;
        if (x.w > 0.5f) li = 3;
        // presence + two index bits, all as ballots (no shuffle needed)
        unsigned long long mh = __ballot(li >= 0);
        unsigned long long m0 = __ballot(li >= 0 && (li & 1));
        unsigned long long m1 = __ballot(li >= 2);

        unsigned gmh = (unsigned)((mh >> (grp * 16)) & 0xFFFFull);
        int oidx;
        if (gmh == 0) {
            oidx = -1;                    // can't happen for exact one-hot rows
        } else {
            int wl   = __builtin_ctz(gmh);        // winning sub-lane (0..15)
            int wbit = grp * 16 + wl;             // bit position in 64-bit masks
            int liw  = (int)((m0 >> wbit) & 1ull) | ((int)((m1 >> wbit) & 1ull) << 1);
            int bi   = (wl << 2) | liw;           // vocab index of the input 1.0
            oidx = s_lut[bi];                     // -1 => zero row
        }

        f32x4 vo;
        vo.x = (oidx == b4i)     ? 1.0f : 0.0f;
        vo.y = (oidx == b4i + 1) ? 1.0f : 0.0f;
        vo.z = (oidx == b4i + 2) ? 1.0f : 0.0f;
        vo.w = (oidx == b4i + 3) ? 1.0f : 0.0f;
        if (c < (size_t)n_chunks)
            __builtin_nontemporal_store(vo, &out4[c]);
    }
}

extern "C" void kernel_launch(void* const* d_in, const int* in_sizes, int n_in,
                              void* d_out, int out_size, void* d_ws, size_t ws_size,
                              hipStream_t stream) {
    const float* inputs = (const float*)d_in[0];  // (B, L, 64) f32 one-hot
    const float* W      = (const float*)d_in[1];  // (64, 128) f32
    const float* b      = (const float*)d_in[2];  // (128,) f32
    float* out = (float*)d_out;

    int n_rows   = in_sizes[0] / VOC;             // B*L = 131072
    int n_chunks = n_rows * 16;                   // float4 chunks (mult of 16)

    int per_block = TPB * CHUNKS;
    int blocks = (n_chunks + per_block - 1) / per_block;  // 512 for B=16,L=8192

    flow_fused_kernel<<<blocks, TPB, 0, stream>>>(inputs, W, b, out, n_chunks);
}